// Round 3
// baseline (120.744 us; speedup 1.0000x reference)
//
#include <hip/hip_runtime.h>
#include <hip/hip_bf16.h>

typedef short short8 __attribute__((ext_vector_type(8)));
typedef float floatx4 __attribute__((ext_vector_type(4)));

#define NEG 0.01f
#define KL_C (-2.8025850929940457f)

// ws layout (float units)
#define W0OFF  131072
#define B0OFF  135168
#define B1OFF  139264
#define W2OFF  143360
#define B2OFF  147456
#define KLPOFF 147520        // 64
#define YPOFF  147584        // 16 * 16384
#define KL_NTOT 278592

__device__ __forceinline__ unsigned bfbits(float x) {
    union { float f; unsigned u; } v; v.f = x;
    return (v.u + 0x7fffu + ((v.u >> 16) & 1u)) >> 16;   // RNE bf16
}
__device__ __forceinline__ unsigned pack2(float lo, float hi) {
    return bfbits(lo) | (bfbits(hi) << 16);
}
// compiler lowers this to v_cvt_pk_bf16_f32 (RNE) on gfx950
__device__ __forceinline__ unsigned pkcvt(float lo, float hi) {
    float2 t; t.x = lo; t.y = hi;
    __hip_bfloat162 b = __float22bfloat162_rn(t);
    union { __hip_bfloat162 b; unsigned u; } c; c.b = b;
    return c.u;
}

// Role-split prep: blocks 0..63 = KL partials + small effective params (fp32);
// blocks 64..127 = per-feature W1 effective weights -> bf16 MFMA B-fragments.
__global__ void bayesnam_prep(const float* __restrict__ wmu0, const float* __restrict__ wls0,
                              const float* __restrict__ bmu0, const float* __restrict__ bls0,
                              const float* __restrict__ ew0,  const float* __restrict__ eb0,
                              const float* __restrict__ wmu1, const float* __restrict__ wls1,
                              const float* __restrict__ bmu1, const float* __restrict__ bls1,
                              const float* __restrict__ ew1,  const float* __restrict__ eb1,
                              const float* __restrict__ wmu2, const float* __restrict__ wls2,
                              const float* __restrict__ bmu2, const float* __restrict__ bls2,
                              const float* __restrict__ ew2,  const float* __restrict__ eb2,
                              float* __restrict__ ws) {
    const int tid = threadIdx.x;
    if (blockIdx.x < 64) {
        __shared__ float red[256];
        float klacc = 0.f;
        for (int idx = blockIdx.x * 256 + tid; idx < KL_NTOT; idx += 64 * 256) {
            const float *mu, *ls, *ew;
            float scale;
            int j, effoff;
            if (idx < 4096)        { j = idx;          mu = wmu0; ls = wls0; ew = ew0; scale = 0.015625f;       effoff = W0OFF; }
            else if (idx < 8192)   { j = idx - 4096;   mu = bmu0; ls = bls0; ew = eb0; scale = 0.015625f;       effoff = B0OFF; }
            else if (idx < 270336) { j = idx - 8192;   mu = wmu1; ls = wls1; ew = ew1; scale = 0.000244140625f; effoff = -1;    }
            else if (idx < 274432) { j = idx - 270336; mu = bmu1; ls = bls1; ew = eb1; scale = 0.015625f;       effoff = B1OFF; }
            else if (idx < 278528) { j = idx - 274432; mu = wmu2; ls = wls2; ew = ew2; scale = 0.015625f;       effoff = W2OFF; }
            else                   { j = idx - 278528; mu = bmu2; ls = bls2; ew = eb2; scale = 1.0f;            effoff = B2OFF; }
            const float m = mu[j];
            const float l = ls[j];
            const float ex = expf(l);
            if (effoff >= 0) ws[effoff + j] = fmaf(ex, ew[j], m);
            klacc += scale * ((KL_C - l) + 50.f * fmaf(ex, ex, m * m));
        }
        red[tid] = klacc;
        __syncthreads();
        for (int s = 128; s > 0; s >>= 1) {
            if (tid < s) red[tid] += red[tid + s];
            __syncthreads();
        }
        if (tid == 0) ws[KLPOFF + blockIdx.x] = red[0];
    } else {
        // B-fragment builder for feature f: layout [f][kk][n][lane][j(8 bf16)]
        __shared__ float w1s[64 * 65];
        const int f = blockIdx.x - 64;
        const size_t base = (size_t)f * 4096;
        for (int i = 0; i < 16; ++i) {
            const int idx = i * 256 + tid;              // idx = k*64 + col
            const int k = idx >> 6, col = idx & 63;
            const float m = wmu1[base + idx];
            const float l = wls1[base + idx];
            const float e = ew1[base + idx];
            w1s[k * 65 + col] = fmaf(expf(l), e, m);
        }
        __syncthreads();
        uint4* outp = (uint4*)((char*)ws + (size_t)f * 8192);
        for (int it = 0; it < 2; ++it) {
            const int g = it * 256 + tid;               // 0..511 = kk*256 + n*64 + lane
            const int lane = g & 63;
            const int n = (g >> 6) & 3;
            const int kk = g >> 8;
            const int k0 = kk * 32 + ((lane >> 4) << 3);
            const int col = n * 16 + (lane & 15);
            float v[8];
            #pragma unroll
            for (int j = 0; j < 8; ++j) v[j] = w1s[(k0 + j) * 65 + col];
            uint4 o;
            o.x = pack2(v[0], v[1]); o.y = pack2(v[2], v[3]);
            o.z = pack2(v[4], v[5]); o.w = pack2(v[6], v[7]);
            outp[g] = o;
        }
    }
}

// Main: per wave 32 batch rows x 64 hidden, 4 features per block (16 chunks).
// No LDS, no barriers. MFMA 16x16x32 bf16, fp32 epilogue, cvt_pk bf16 A-build.
__global__ __launch_bounds__(256, 8) void bayesnam_main(const float* __restrict__ fin,
                                                        const float* __restrict__ ws,
                                                        float* __restrict__ ypart) {
    const int tid = threadIdx.x;
    const int l   = tid & 63;
    const int wid = tid >> 6;
    const int l15 = l & 15;
    const int lg  = l >> 4;                       // 0..3
    const int rowbase = blockIdx.x * 128 + wid * 32;
    const int f0 = blockIdx.y * 4;

    const uint4* __restrict__ w1q = (const uint4*)ws;

    // x for all 4 features of this chunk, both row tiles (one dwordx4 each)
    const floatx4 x0v = *(const floatx4*)(fin + (size_t)(rowbase + l15) * 64 + f0);
    const floatx4 x1v = *(const floatx4*)(fin + (size_t)(rowbase + 16 + l15) * 64 + f0);

    float yacc[2][4];
    #pragma unroll
    for (int r = 0; r < 2; ++r)
        #pragma unroll
        for (int q = 0; q < 4; ++q) yacc[r][q] = 0.f;
    float b2sum = 0.f;

    #pragma unroll
    for (int fi = 0; fi < 4; ++fi) {
        const int f = f0 + fi;
        const float* w0p = ws + W0OFF + f * 64;
        const float* b0p = ws + B0OFF + f * 64;
        const float* b1p = ws + B1OFF + f * 64;
        const float* w2p = ws + W2OFF + f * 64;
        const float x0 = x0v[fi];
        const float x1 = x1v[fi];

        floatx4 acc[2][4];
        #pragma unroll
        for (int n = 0; n < 4; ++n) {
            const float bv = b1p[n * 16 + l15];
            acc[0][n] = floatx4{bv, bv, bv, bv};
            acc[1][n] = floatx4{bv, bv, bv, bv};
        }

        #pragma unroll
        for (int kk = 0; kk < 2; ++kk) {
            const int kb = kk * 32 + lg * 8;
            const floatx4 w0a = *(const floatx4*)(w0p + kb);
            const floatx4 w0b = *(const floatx4*)(w0p + kb + 4);
            const floatx4 b0a = *(const floatx4*)(b0p + kb);
            const floatx4 b0b = *(const floatx4*)(b0p + kb + 4);

            float h[8], g[8];
            #pragma unroll
            for (int j = 0; j < 4; ++j) {
                float v = fmaf(x0, w0a[j], b0a[j]); h[j]     = fmaxf(v, NEG * v);
                v = fmaf(x1, w0a[j], b0a[j]);       g[j]     = fmaxf(v, NEG * v);
                v = fmaf(x0, w0b[j], b0b[j]);       h[j + 4] = fmaxf(v, NEG * v);
                v = fmaf(x1, w0b[j], b0b[j]);       g[j + 4] = fmaxf(v, NEG * v);
            }
            union U { short8 s; unsigned u[4]; };
            U ua, ub;
            #pragma unroll
            for (int j = 0; j < 4; ++j) {
                ua.u[j] = pkcvt(h[2 * j], h[2 * j + 1]);
                ub.u[j] = pkcvt(g[2 * j], g[2 * j + 1]);
            }
            const short8 a0 = ua.s;
            const short8 a1 = ub.s;

            const uint4* bp = w1q + (size_t)(f * 8 + kk * 4) * 64 + l;
            short8 bfr[4];
            #pragma unroll
            for (int n = 0; n < 4; ++n) {
                const uint4 t = bp[n * 64];
                bfr[n] = *(const short8*)&t;
            }
            #pragma unroll
            for (int n = 0; n < 4; ++n) {
                acc[0][n] = __builtin_amdgcn_mfma_f32_16x16x32_bf16(a0, bfr[n], acc[0][n], 0, 0, 0);
                acc[1][n] = __builtin_amdgcn_mfma_f32_16x16x32_bf16(a1, bfr[n], acc[1][n], 0, 0, 0);
            }
        }

        // epilogue: leaky + dot with w2 (fp32)
        #pragma unroll
        for (int n = 0; n < 4; ++n) {
            const float w2v = w2p[n * 16 + l15];
            #pragma unroll
            for (int r = 0; r < 2; ++r)
                #pragma unroll
                for (int q = 0; q < 4; ++q) {
                    float v = acc[r][n][q];
                    v = fmaxf(v, NEG * v);
                    yacc[r][q] = fmaf(v, w2v, yacc[r][q]);
                }
        }
        b2sum += ws[B2OFF + f];
    }

    // reduce over the 16 column-lanes (C layout: col = l&15, row = lg*4+q)
    #pragma unroll
    for (int r = 0; r < 2; ++r)
        #pragma unroll
        for (int q = 0; q < 4; ++q) {
            float v = yacc[r][q];
            v += __shfl_xor(v, 1, 64);
            v += __shfl_xor(v, 2, 64);
            v += __shfl_xor(v, 4, 64);
            v += __shfl_xor(v, 8, 64);
            yacc[r][q] = v;
        }
    if (l15 == 0) {
        float* yp = ypart + (size_t)blockIdx.y * 16384 + rowbase;
        #pragma unroll
        for (int r = 0; r < 2; ++r) {
            floatx4 o;
            #pragma unroll
            for (int q = 0; q < 4; ++q) o[q] = yacc[r][q] + b2sum;
            *(floatx4*)(yp + r * 16 + lg * 4) = o;
        }
    }
}

__global__ void bayesnam_finish(const float* __restrict__ ws, const float* __restrict__ bias,
                                float* __restrict__ out) {
    const int b = blockIdx.x * 256 + threadIdx.x;
    float acc = bias[0];
    #pragma unroll
    for (int c = 0; c < 16; ++c) acc += ws[YPOFF + c * 16384 + b];
    out[b] = acc;
    if (blockIdx.x == 0 && threadIdx.x == 0) {
        float k = 0.f;
        for (int i = 0; i < 64; ++i) k += ws[KLPOFF + i];
        out[16384] = k;
    }
}

extern "C" void kernel_launch(void* const* d_in, const int* in_sizes, int n_in,
                              void* d_out, int out_size, void* d_ws, size_t ws_size,
                              hipStream_t stream) {
    const float* fin  = (const float*)d_in[0];
    const float* wmu0 = (const float*)d_in[1];
    const float* wls0 = (const float*)d_in[2];
    const float* bmu0 = (const float*)d_in[3];
    const float* bls0 = (const float*)d_in[4];
    const float* ew0  = (const float*)d_in[5];
    const float* eb0  = (const float*)d_in[6];
    const float* wmu1 = (const float*)d_in[7];
    const float* wls1 = (const float*)d_in[8];
    const float* bmu1 = (const float*)d_in[9];
    const float* bls1 = (const float*)d_in[10];
    const float* ew1  = (const float*)d_in[11];
    const float* eb1  = (const float*)d_in[12];
    const float* wmu2 = (const float*)d_in[13];
    const float* wls2 = (const float*)d_in[14];
    const float* bmu2 = (const float*)d_in[15];
    const float* bls2 = (const float*)d_in[16];
    const float* ew2  = (const float*)d_in[17];
    const float* eb2  = (const float*)d_in[18];
    const float* bias = (const float*)d_in[19];

    float* ws  = (float*)d_ws;
    float* out = (float*)d_out;

    hipLaunchKernelGGL(bayesnam_prep, dim3(128), dim3(256), 0, stream,
                       wmu0, wls0, bmu0, bls0, ew0, eb0,
                       wmu1, wls1, bmu1, bls1, ew1, eb1,
                       wmu2, wls2, bmu2, bls2, ew2, eb2, ws);

    hipLaunchKernelGGL(bayesnam_main, dim3(128, 16), dim3(256), 0, stream,
                       fin, ws, ws + YPOFF);

    hipLaunchKernelGGL(bayesnam_finish, dim3(64), dim3(256), 0, stream,
                       ws, bias, out);
}

// Round 4
// 91.378 us; speedup vs baseline: 1.3214x; 1.3214x over previous
//
#include <hip/hip_runtime.h>
#include <hip/hip_bf16.h>

typedef short short8 __attribute__((ext_vector_type(8)));
typedef float floatx4 __attribute__((ext_vector_type(4)));

#define NEG 0.01f
#define KL_C (-2.8025850929940457f)

// ws layout (float units)
#define W0OFF  131072
#define B0OFF  135168
#define B1OFF  139264
#define W2OFF  143360
#define B2OFF  147456
#define KLPOFF 147520        // 64
#define YPOFF  147584        // 16 * 16384
#define KL_NTOT 278592

__device__ __forceinline__ unsigned bfbits(float x) {
    union { float f; unsigned u; } v; v.f = x;
    return (v.u + 0x7fffu + ((v.u >> 16) & 1u)) >> 16;   // RNE bf16
}
__device__ __forceinline__ unsigned pack2(float lo, float hi) {
    return bfbits(lo) | (bfbits(hi) << 16);
}
// compiler lowers this to v_cvt_pk_bf16_f32 (RNE) on gfx950
__device__ __forceinline__ unsigned pkcvt(float lo, float hi) {
    float2 t; t.x = lo; t.y = hi;
    __hip_bfloat162 b = __float22bfloat162_rn(t);
    union { __hip_bfloat162 b; unsigned u; } c; c.b = b;
    return c.u;
}

// Role-split prep: blocks 0..63 = KL partials + small effective params (fp32);
// blocks 64..127 = per-feature W1 effective weights -> bf16 MFMA B-fragments.
__global__ void bayesnam_prep(const float* __restrict__ wmu0, const float* __restrict__ wls0,
                              const float* __restrict__ bmu0, const float* __restrict__ bls0,
                              const float* __restrict__ ew0,  const float* __restrict__ eb0,
                              const float* __restrict__ wmu1, const float* __restrict__ wls1,
                              const float* __restrict__ bmu1, const float* __restrict__ bls1,
                              const float* __restrict__ ew1,  const float* __restrict__ eb1,
                              const float* __restrict__ wmu2, const float* __restrict__ wls2,
                              const float* __restrict__ bmu2, const float* __restrict__ bls2,
                              const float* __restrict__ ew2,  const float* __restrict__ eb2,
                              float* __restrict__ ws) {
    const int tid = threadIdx.x;
    if (blockIdx.x < 64) {
        __shared__ float red[256];
        float klacc = 0.f;
        for (int idx = blockIdx.x * 256 + tid; idx < KL_NTOT; idx += 64 * 256) {
            const float *mu, *ls, *ew;
            float scale;
            int j, effoff;
            if (idx < 4096)        { j = idx;          mu = wmu0; ls = wls0; ew = ew0; scale = 0.015625f;       effoff = W0OFF; }
            else if (idx < 8192)   { j = idx - 4096;   mu = bmu0; ls = bls0; ew = eb0; scale = 0.015625f;       effoff = B0OFF; }
            else if (idx < 270336) { j = idx - 8192;   mu = wmu1; ls = wls1; ew = ew1; scale = 0.000244140625f; effoff = -1;    }
            else if (idx < 274432) { j = idx - 270336; mu = bmu1; ls = bls1; ew = eb1; scale = 0.015625f;       effoff = B1OFF; }
            else if (idx < 278528) { j = idx - 274432; mu = wmu2; ls = wls2; ew = ew2; scale = 0.015625f;       effoff = W2OFF; }
            else                   { j = idx - 278528; mu = bmu2; ls = bls2; ew = eb2; scale = 1.0f;            effoff = B2OFF; }
            const float m = mu[j];
            const float l = ls[j];
            const float ex = expf(l);
            if (effoff >= 0) ws[effoff + j] = fmaf(ex, ew[j], m);
            klacc += scale * ((KL_C - l) + 50.f * fmaf(ex, ex, m * m));
        }
        red[tid] = klacc;
        __syncthreads();
        for (int s = 128; s > 0; s >>= 1) {
            if (tid < s) red[tid] += red[tid + s];
            __syncthreads();
        }
        if (tid == 0) ws[KLPOFF + blockIdx.x] = red[0];
    } else {
        // B-fragment builder for feature f: layout [f][kk][n][lane][j(8 bf16)]
        __shared__ float w1s[64 * 65];
        const int f = blockIdx.x - 64;
        const size_t base = (size_t)f * 4096;
        for (int i = 0; i < 16; ++i) {
            const int idx = i * 256 + tid;              // idx = k*64 + col
            const int k = idx >> 6, col = idx & 63;
            const float m = wmu1[base + idx];
            const float l = wls1[base + idx];
            const float e = ew1[base + idx];
            w1s[k * 65 + col] = fmaf(expf(l), e, m);
        }
        __syncthreads();
        uint4* outp = (uint4*)((char*)ws + (size_t)f * 8192);
        for (int it = 0; it < 2; ++it) {
            const int g = it * 256 + tid;               // 0..511 = kk*256 + n*64 + lane
            const int lane = g & 63;
            const int n = (g >> 6) & 3;
            const int kk = g >> 8;
            const int k0 = kk * 32 + ((lane >> 4) << 3);
            const int col = n * 16 + (lane & 15);
            float v[8];
            #pragma unroll
            for (int j = 0; j < 8; ++j) v[j] = w1s[(k0 + j) * 65 + col];
            uint4 o;
            o.x = pack2(v[0], v[1]); o.y = pack2(v[2], v[3]);
            o.z = pack2(v[4], v[5]); o.w = pack2(v[6], v[7]);
            outp[g] = o;
        }
    }
}

// Main: per wave 32 batch rows x 64 hidden, 4 features per block (16 chunks).
// No LDS, no barriers. MFMA 16x16x32 bf16, fp32 epilogue, cvt_pk bf16 A-build.
// Feature loop NOT unrolled (R3 lesson: full unroll + tight VGPR cap = spill).
__global__ __launch_bounds__(256, 8) void bayesnam_main(const float* __restrict__ fin,
                                                        const float* __restrict__ ws,
                                                        float* __restrict__ ypart) {
    const int tid = threadIdx.x;
    const int l   = tid & 63;
    const int wid = tid >> 6;
    const int l15 = l & 15;
    const int lg  = l >> 4;                       // 0..3
    const int rowbase = blockIdx.x * 128 + wid * 32;
    const int f0 = blockIdx.y * 4;

    const uint4* __restrict__ w1q = (const uint4*)ws;

    // x for all 4 features of this chunk, both row tiles (one dwordx4 each)
    const floatx4 x0v = *(const floatx4*)(fin + (size_t)(rowbase + l15) * 64 + f0);
    const floatx4 x1v = *(const floatx4*)(fin + (size_t)(rowbase + 16 + l15) * 64 + f0);

    float yacc[2][4];
    #pragma unroll
    for (int r = 0; r < 2; ++r)
        #pragma unroll
        for (int q = 0; q < 4; ++q) yacc[r][q] = 0.f;
    float b2sum = 0.f;

    #pragma unroll 1
    for (int fi = 0; fi < 4; ++fi) {
        const int f = f0 + fi;
        const float* w0p = ws + W0OFF + f * 64;
        const float* b0p = ws + B0OFF + f * 64;
        const float* b1p = ws + B1OFF + f * 64;
        const float* w2p = ws + W2OFF + f * 64;
        const float x0 = x0v[fi];
        const float x1 = x1v[fi];

        floatx4 acc[2][4];
        #pragma unroll
        for (int n = 0; n < 4; ++n) {
            const float bv = b1p[n * 16 + l15];
            acc[0][n] = floatx4{bv, bv, bv, bv};
            acc[1][n] = floatx4{bv, bv, bv, bv};
        }

        #pragma unroll
        for (int kk = 0; kk < 2; ++kk) {
            const int kb = kk * 32 + lg * 8;
            const floatx4 w0a = *(const floatx4*)(w0p + kb);
            const floatx4 w0b = *(const floatx4*)(w0p + kb + 4);
            const floatx4 b0a = *(const floatx4*)(b0p + kb);
            const floatx4 b0b = *(const floatx4*)(b0p + kb + 4);

            float h[8], g[8];
            #pragma unroll
            for (int j = 0; j < 4; ++j) {
                float v = fmaf(x0, w0a[j], b0a[j]); h[j]     = fmaxf(v, NEG * v);
                v = fmaf(x1, w0a[j], b0a[j]);       g[j]     = fmaxf(v, NEG * v);
                v = fmaf(x0, w0b[j], b0b[j]);       h[j + 4] = fmaxf(v, NEG * v);
                v = fmaf(x1, w0b[j], b0b[j]);       g[j + 4] = fmaxf(v, NEG * v);
            }
            union U { short8 s; unsigned u[4]; };
            U ua, ub;
            #pragma unroll
            for (int j = 0; j < 4; ++j) {
                ua.u[j] = pkcvt(h[2 * j], h[2 * j + 1]);
                ub.u[j] = pkcvt(g[2 * j], g[2 * j + 1]);
            }
            const short8 a0 = ua.s;
            const short8 a1 = ub.s;

            const uint4* bp = w1q + (size_t)(f * 8 + kk * 4) * 64 + l;
            short8 bfr[4];
            #pragma unroll
            for (int n = 0; n < 4; ++n) {
                const uint4 t = bp[n * 64];
                bfr[n] = *(const short8*)&t;
            }
            #pragma unroll
            for (int n = 0; n < 4; ++n) {
                acc[0][n] = __builtin_amdgcn_mfma_f32_16x16x32_bf16(a0, bfr[n], acc[0][n], 0, 0, 0);
                acc[1][n] = __builtin_amdgcn_mfma_f32_16x16x32_bf16(a1, bfr[n], acc[1][n], 0, 0, 0);
            }
        }

        // epilogue: leaky + dot with w2 (fp32)
        #pragma unroll
        for (int n = 0; n < 4; ++n) {
            const float w2v = w2p[n * 16 + l15];
            #pragma unroll
            for (int r = 0; r < 2; ++r)
                #pragma unroll
                for (int q = 0; q < 4; ++q) {
                    float v = acc[r][n][q];
                    v = fmaxf(v, NEG * v);
                    yacc[r][q] = fmaf(v, w2v, yacc[r][q]);
                }
        }
        b2sum += ws[B2OFF + f];
    }

    // reduce over the 16 column-lanes (C layout: col = l&15, row = lg*4+q)
    #pragma unroll
    for (int r = 0; r < 2; ++r)
        #pragma unroll
        for (int q = 0; q < 4; ++q) {
            float v = yacc[r][q];
            v += __shfl_xor(v, 1, 64);
            v += __shfl_xor(v, 2, 64);
            v += __shfl_xor(v, 4, 64);
            v += __shfl_xor(v, 8, 64);
            yacc[r][q] = v;
        }
    if (l15 == 0) {
        float* yp = ypart + (size_t)blockIdx.y * 16384 + rowbase;
        #pragma unroll
        for (int r = 0; r < 2; ++r) {
            floatx4 o;
            #pragma unroll
            for (int q = 0; q < 4; ++q) o[q] = yacc[r][q] + b2sum;
            *(floatx4*)(yp + r * 16 + lg * 4) = o;
        }
    }
}

__global__ void bayesnam_finish(const float* __restrict__ ws, const float* __restrict__ bias,
                                float* __restrict__ out) {
    const int b = blockIdx.x * 256 + threadIdx.x;
    float acc = bias[0];
    #pragma unroll
    for (int c = 0; c < 16; ++c) acc += ws[YPOFF + c * 16384 + b];
    out[b] = acc;
    if (blockIdx.x == 0 && threadIdx.x == 0) {
        float k = 0.f;
        for (int i = 0; i < 64; ++i) k += ws[KLPOFF + i];
        out[16384] = k;
    }
}

extern "C" void kernel_launch(void* const* d_in, const int* in_sizes, int n_in,
                              void* d_out, int out_size, void* d_ws, size_t ws_size,
                              hipStream_t stream) {
    const float* fin  = (const float*)d_in[0];
    const float* wmu0 = (const float*)d_in[1];
    const float* wls0 = (const float*)d_in[2];
    const float* bmu0 = (const float*)d_in[3];
    const float* bls0 = (const float*)d_in[4];
    const float* ew0  = (const float*)d_in[5];
    const float* eb0  = (const float*)d_in[6];
    const float* wmu1 = (const float*)d_in[7];
    const float* wls1 = (const float*)d_in[8];
    const float* bmu1 = (const float*)d_in[9];
    const float* bls1 = (const float*)d_in[10];
    const float* ew1  = (const float*)d_in[11];
    const float* eb1  = (const float*)d_in[12];
    const float* wmu2 = (const float*)d_in[13];
    const float* wls2 = (const float*)d_in[14];
    const float* bmu2 = (const float*)d_in[15];
    const float* bls2 = (const float*)d_in[16];
    const float* ew2  = (const float*)d_in[17];
    const float* eb2  = (const float*)d_in[18];
    const float* bias = (const float*)d_in[19];

    float* ws  = (float*)d_ws;
    float* out = (float*)d_out;

    hipLaunchKernelGGL(bayesnam_prep, dim3(128), dim3(256), 0, stream,
                       wmu0, wls0, bmu0, bls0, ew0, eb0,
                       wmu1, wls1, bmu1, bls1, ew1, eb1,
                       wmu2, wls2, bmu2, bls2, ew2, eb2, ws);

    hipLaunchKernelGGL(bayesnam_main, dim3(128, 16), dim3(256), 0, stream,
                       fin, ws, ws + YPOFF);

    hipLaunchKernelGGL(bayesnam_finish, dim3(64), dim3(256), 0, stream,
                       ws, bias, out);
}

// Round 5
// 39.457 us; speedup vs baseline: 3.0602x; 2.3159x over previous
//
#include <hip/hip_runtime.h>
#include <hip/hip_bf16.h>

typedef short short8 __attribute__((ext_vector_type(8)));
typedef float floatx4 __attribute__((ext_vector_type(4)));

#define NEG 0.01f
#define KL_C (-2.8025850929940457f)

// ws layout (float units)
#define W0OFF  131072
#define B0OFF  135168
#define B1OFF  139264
#define W2OFF  143360
#define B2OFF  147456
#define KLPOFF 147520        // 64
#define YPOFF  147584        // 16 * 16384
#define KL_NTOT 278592

__device__ __forceinline__ unsigned bfbits(float x) {
    union { float f; unsigned u; } v; v.f = x;
    return (v.u + 0x7fffu + ((v.u >> 16) & 1u)) >> 16;   // RNE bf16
}
__device__ __forceinline__ unsigned pack2(float lo, float hi) {
    return bfbits(lo) | (bfbits(hi) << 16);
}
// compiler lowers this to v_cvt_pk_bf16_f32 (RNE) on gfx950
__device__ __forceinline__ unsigned pkcvt(float lo, float hi) {
    float2 t; t.x = lo; t.y = hi;
    __hip_bfloat162 b = __float22bfloat162_rn(t);
    union { __hip_bfloat162 b; unsigned u; } c; c.b = b;
    return c.u;
}

// Role-split prep: blocks 0..63 = KL partials + small effective params (fp32);
// blocks 64..127 = per-feature W1 effective weights -> bf16 MFMA B-fragments.
__global__ void bayesnam_prep(const float* __restrict__ wmu0, const float* __restrict__ wls0,
                              const float* __restrict__ bmu0, const float* __restrict__ bls0,
                              const float* __restrict__ ew0,  const float* __restrict__ eb0,
                              const float* __restrict__ wmu1, const float* __restrict__ wls1,
                              const float* __restrict__ bmu1, const float* __restrict__ bls1,
                              const float* __restrict__ ew1,  const float* __restrict__ eb1,
                              const float* __restrict__ wmu2, const float* __restrict__ wls2,
                              const float* __restrict__ bmu2, const float* __restrict__ bls2,
                              const float* __restrict__ ew2,  const float* __restrict__ eb2,
                              float* __restrict__ ws) {
    const int tid = threadIdx.x;
    if (blockIdx.x < 64) {
        __shared__ float red[256];
        float klacc = 0.f;
        for (int idx = blockIdx.x * 256 + tid; idx < KL_NTOT; idx += 64 * 256) {
            const float *mu, *ls, *ew;
            float scale;
            int j, effoff;
            if (idx < 4096)        { j = idx;          mu = wmu0; ls = wls0; ew = ew0; scale = 0.015625f;       effoff = W0OFF; }
            else if (idx < 8192)   { j = idx - 4096;   mu = bmu0; ls = bls0; ew = eb0; scale = 0.015625f;       effoff = B0OFF; }
            else if (idx < 270336) { j = idx - 8192;   mu = wmu1; ls = wls1; ew = ew1; scale = 0.000244140625f; effoff = -1;    }
            else if (idx < 274432) { j = idx - 270336; mu = bmu1; ls = bls1; ew = eb1; scale = 0.015625f;       effoff = B1OFF; }
            else if (idx < 278528) { j = idx - 274432; mu = wmu2; ls = wls2; ew = ew2; scale = 0.015625f;       effoff = W2OFF; }
            else                   { j = idx - 278528; mu = bmu2; ls = bls2; ew = eb2; scale = 1.0f;            effoff = B2OFF; }
            const float m = mu[j];
            const float l = ls[j];
            const float ex = expf(l);
            if (effoff >= 0) ws[effoff + j] = fmaf(ex, ew[j], m);
            klacc += scale * ((KL_C - l) + 50.f * fmaf(ex, ex, m * m));
        }
        red[tid] = klacc;
        __syncthreads();
        for (int s = 128; s > 0; s >>= 1) {
            if (tid < s) red[tid] += red[tid + s];
            __syncthreads();
        }
        if (tid == 0) ws[KLPOFF + blockIdx.x] = red[0];
    } else {
        // B-fragment builder for feature f: layout [f][kk][n][lane][j(8 bf16)]
        __shared__ float w1s[64 * 65];
        const int f = blockIdx.x - 64;
        const size_t base = (size_t)f * 4096;
        for (int i = 0; i < 16; ++i) {
            const int idx = i * 256 + tid;              // idx = k*64 + col
            const int k = idx >> 6, col = idx & 63;
            const float m = wmu1[base + idx];
            const float l = wls1[base + idx];
            const float e = ew1[base + idx];
            w1s[k * 65 + col] = fmaf(expf(l), e, m);
        }
        __syncthreads();
        uint4* outp = (uint4*)((char*)ws + (size_t)f * 8192);
        for (int it = 0; it < 2; ++it) {
            const int g = it * 256 + tid;               // 0..511 = kk*256 + n*64 + lane
            const int lane = g & 63;
            const int n = (g >> 6) & 3;
            const int kk = g >> 8;
            const int k0 = kk * 32 + ((lane >> 4) << 3);
            const int col = n * 16 + (lane & 15);
            float v[8];
            #pragma unroll
            for (int j = 0; j < 8; ++j) v[j] = w1s[(k0 + j) * 65 + col];
            uint4 o;
            o.x = pack2(v[0], v[1]); o.y = pack2(v[2], v[3]);
            o.z = pack2(v[4], v[5]); o.w = pack2(v[6], v[7]);
            outp[g] = o;
        }
    }
}

// Main: per wave 32 batch rows x 64 hidden, 4 features per block (16 chunks).
// No LDS, no barriers. MFMA 16x16x32 bf16, fp32 epilogue, cvt_pk bf16 A-build.
// launch_bounds(256,4): VGPR cap 128 — natural alloc ~56 (R2), HW can then
// co-schedule 8 blocks/CU on its own. (256,8) caused catastrophic spill (R4).
__global__ __launch_bounds__(256, 4) void bayesnam_main(const float* __restrict__ fin,
                                                        const float* __restrict__ ws,
                                                        float* __restrict__ ypart) {
    const int tid = threadIdx.x;
    const int l   = tid & 63;
    const int wid = tid >> 6;
    const int l15 = l & 15;
    const int lg  = l >> 4;                       // 0..3
    const int rowbase = blockIdx.x * 128 + wid * 32;
    const int f0 = blockIdx.y * 4;

    const uint4* __restrict__ w1q = (const uint4*)ws;

    // x for all 4 features of this chunk, both row tiles (one dwordx4 each)
    const floatx4 x0v = *(const floatx4*)(fin + (size_t)(rowbase + l15) * 64 + f0);
    const floatx4 x1v = *(const floatx4*)(fin + (size_t)(rowbase + 16 + l15) * 64 + f0);

    float yacc[2][4];
    #pragma unroll
    for (int r = 0; r < 2; ++r)
        #pragma unroll
        for (int q = 0; q < 4; ++q) yacc[r][q] = 0.f;
    float b2sum = 0.f;

    #pragma unroll 1
    for (int fi = 0; fi < 4; ++fi) {
        const int f = f0 + fi;
        const float* w0p = ws + W0OFF + f * 64;
        const float* b0p = ws + B0OFF + f * 64;
        const float* b1p = ws + B1OFF + f * 64;
        const float* w2p = ws + W2OFF + f * 64;
        const float x0 = x0v[fi];
        const float x1 = x1v[fi];

        floatx4 acc[2][4];
        #pragma unroll
        for (int n = 0; n < 4; ++n) {
            const float bv = b1p[n * 16 + l15];
            acc[0][n] = floatx4{bv, bv, bv, bv};
            acc[1][n] = floatx4{bv, bv, bv, bv};
        }

        #pragma unroll
        for (int kk = 0; kk < 2; ++kk) {
            const int kb = kk * 32 + lg * 8;
            const floatx4 w0a = *(const floatx4*)(w0p + kb);
            const floatx4 w0b = *(const floatx4*)(w0p + kb + 4);
            const floatx4 b0a = *(const floatx4*)(b0p + kb);
            const floatx4 b0b = *(const floatx4*)(b0p + kb + 4);

            float h[8], g[8];
            #pragma unroll
            for (int j = 0; j < 4; ++j) {
                float v = fmaf(x0, w0a[j], b0a[j]); h[j]     = fmaxf(v, NEG * v);
                v = fmaf(x1, w0a[j], b0a[j]);       g[j]     = fmaxf(v, NEG * v);
                v = fmaf(x0, w0b[j], b0b[j]);       h[j + 4] = fmaxf(v, NEG * v);
                v = fmaf(x1, w0b[j], b0b[j]);       g[j + 4] = fmaxf(v, NEG * v);
            }
            union U { short8 s; unsigned u[4]; };
            U ua, ub;
            #pragma unroll
            for (int j = 0; j < 4; ++j) {
                ua.u[j] = pkcvt(h[2 * j], h[2 * j + 1]);
                ub.u[j] = pkcvt(g[2 * j], g[2 * j + 1]);
            }
            const short8 a0 = ua.s;
            const short8 a1 = ub.s;

            const uint4* bp = w1q + (size_t)(f * 8 + kk * 4) * 64 + l;
            short8 bfr[4];
            #pragma unroll
            for (int n = 0; n < 4; ++n) {
                const uint4 t = bp[n * 64];
                bfr[n] = *(const short8*)&t;
            }
            #pragma unroll
            for (int n = 0; n < 4; ++n) {
                acc[0][n] = __builtin_amdgcn_mfma_f32_16x16x32_bf16(a0, bfr[n], acc[0][n], 0, 0, 0);
                acc[1][n] = __builtin_amdgcn_mfma_f32_16x16x32_bf16(a1, bfr[n], acc[1][n], 0, 0, 0);
            }
        }

        // epilogue: leaky + dot with w2 (fp32)
        #pragma unroll
        for (int n = 0; n < 4; ++n) {
            const float w2v = w2p[n * 16 + l15];
            #pragma unroll
            for (int r = 0; r < 2; ++r)
                #pragma unroll
                for (int q = 0; q < 4; ++q) {
                    float v = acc[r][n][q];
                    v = fmaxf(v, NEG * v);
                    yacc[r][q] = fmaf(v, w2v, yacc[r][q]);
                }
        }
        b2sum += ws[B2OFF + f];
    }

    // reduce over the 16 column-lanes (C layout: col = l&15, row = lg*4+q)
    #pragma unroll
    for (int r = 0; r < 2; ++r)
        #pragma unroll
        for (int q = 0; q < 4; ++q) {
            float v = yacc[r][q];
            v += __shfl_xor(v, 1, 64);
            v += __shfl_xor(v, 2, 64);
            v += __shfl_xor(v, 4, 64);
            v += __shfl_xor(v, 8, 64);
            yacc[r][q] = v;
        }
    if (l15 == 0) {
        float* yp = ypart + (size_t)blockIdx.y * 16384 + rowbase;
        #pragma unroll
        for (int r = 0; r < 2; ++r) {
            floatx4 o;
            #pragma unroll
            for (int q = 0; q < 4; ++q) o[q] = yacc[r][q] + b2sum;
            *(floatx4*)(yp + r * 16 + lg * 4) = o;
        }
    }
}

__global__ void bayesnam_finish(const float* __restrict__ ws, const float* __restrict__ bias,
                                float* __restrict__ out) {
    const int b = blockIdx.x * 256 + threadIdx.x;
    float acc = bias[0];
    #pragma unroll
    for (int c = 0; c < 16; ++c) acc += ws[YPOFF + c * 16384 + b];
    out[b] = acc;
    if (blockIdx.x == 0 && threadIdx.x == 0) {
        float k = 0.f;
        for (int i = 0; i < 64; ++i) k += ws[KLPOFF + i];
        out[16384] = k;
    }
}

extern "C" void kernel_launch(void* const* d_in, const int* in_sizes, int n_in,
                              void* d_out, int out_size, void* d_ws, size_t ws_size,
                              hipStream_t stream) {
    const float* fin  = (const float*)d_in[0];
    const float* wmu0 = (const float*)d_in[1];
    const float* wls0 = (const float*)d_in[2];
    const float* bmu0 = (const float*)d_in[3];
    const float* bls0 = (const float*)d_in[4];
    const float* ew0  = (const float*)d_in[5];
    const float* eb0  = (const float*)d_in[6];
    const float* wmu1 = (const float*)d_in[7];
    const float* wls1 = (const float*)d_in[8];
    const float* bmu1 = (const float*)d_in[9];
    const float* bls1 = (const float*)d_in[10];
    const float* ew1  = (const float*)d_in[11];
    const float* eb1  = (const float*)d_in[12];
    const float* wmu2 = (const float*)d_in[13];
    const float* wls2 = (const float*)d_in[14];
    const float* bmu2 = (const float*)d_in[15];
    const float* bls2 = (const float*)d_in[16];
    const float* ew2  = (const float*)d_in[17];
    const float* eb2  = (const float*)d_in[18];
    const float* bias = (const float*)d_in[19];

    float* ws  = (float*)d_ws;
    float* out = (float*)d_out;

    hipLaunchKernelGGL(bayesnam_prep, dim3(128), dim3(256), 0, stream,
                       wmu0, wls0, bmu0, bls0, ew0, eb0,
                       wmu1, wls1, bmu1, bls1, ew1, eb1,
                       wmu2, wls2, bmu2, bls2, ew2, eb2, ws);

    hipLaunchKernelGGL(bayesnam_main, dim3(128, 16), dim3(256), 0, stream,
                       fin, ws, ws + YPOFF);

    hipLaunchKernelGGL(bayesnam_finish, dim3(64), dim3(256), 0, stream,
                       ws, bias, out);
}

// Round 7
// 32.004 us; speedup vs baseline: 3.7728x; 1.2329x over previous
//
#include <hip/hip_runtime.h>
#include <hip/hip_fp16.h>

typedef _Float16 f16x8 __attribute__((ext_vector_type(8)));
typedef float floatx4 __attribute__((ext_vector_type(4)));

#define NEG 0.01f
#define KL_C (-2.8025850929940457f)

// ws layout (float units)
// [0 .. 131071]   W1 f16 MFMA B-fragments: 64 f x 512 uint4 (512 KB)
#define W0HOFF 131072        // 4096 halves (2048 floats)
#define B0HOFF 133120        // 4096 halves
#define B1OFF  135168        // 4096 f32
#define W2OFF  139264        // 4096 f32
#define B2OFF  143360        // 64 f32
#define KLPOFF 143424        // 136 f32 partials

// prep grid: blocks 0..127 = (feature f = bx>>1, k-half kk = bx&1):
//   compute W1 eff (fp32), W1-KL partial, pack f16 fragments.
// blocks 128..135: small tensors (w0,b0,b1,w2,b2) eff + KL, d_out = bias init.
__global__ void bayesnam_prep(const float* __restrict__ wmu0, const float* __restrict__ wls0,
                              const float* __restrict__ bmu0, const float* __restrict__ bls0,
                              const float* __restrict__ ew0,  const float* __restrict__ eb0,
                              const float* __restrict__ wmu1, const float* __restrict__ wls1,
                              const float* __restrict__ bmu1, const float* __restrict__ bls1,
                              const float* __restrict__ ew1,  const float* __restrict__ eb1,
                              const float* __restrict__ wmu2, const float* __restrict__ wls2,
                              const float* __restrict__ bmu2, const float* __restrict__ bls2,
                              const float* __restrict__ ew2,  const float* __restrict__ eb2,
                              const float* __restrict__ bias,
                              float* __restrict__ ws, float* __restrict__ out) {
    const int tid = threadIdx.x;
    const int bx  = blockIdx.x;
    __shared__ float red[256];
    if (bx < 128) {
        const int f  = bx >> 1;
        const int kk = bx & 1;
        __shared__ float w1s[32 * 65];
        const size_t base = (size_t)f * 4096 + (size_t)kk * 2048;
        float klacc = 0.f;
        #pragma unroll
        for (int i = 0; i < 8; ++i) {
            const int idx = i * 256 + tid;           // klocal*64 + col
            const float m = wmu1[base + idx];
            const float l = wls1[base + idx];
            const float e = ew1[base + idx];
            const float ex = expf(l);
            w1s[(idx >> 6) * 65 + (idx & 63)] = fmaf(ex, e, m);
            klacc += (KL_C - l) + 50.f * fmaf(ex, ex, m * m);
        }
        red[tid] = klacc * 0.000244140625f;          // 1/4096 (per-feature mean)
        __syncthreads();
        for (int s = 128; s > 0; s >>= 1) {
            if (tid < s) red[tid] += red[tid + s];
            __syncthreads();
        }
        if (tid == 0) ws[KLPOFF + bx] = red[0];
        // fragment pack: 256 units = n(2b) x lane(6b); layout [f][kk][n][lane][8 f16]
        const int lane = tid & 63;
        const int n    = tid >> 6;
        const int k0   = (lane >> 4) << 3;
        const int col  = n * 16 + (lane & 15);
        union { _Float16 h[8]; uint4 u; } fr;
        #pragma unroll
        for (int j = 0; j < 8; ++j) fr.h[j] = (_Float16)w1s[(k0 + j) * 65 + col];
        ((uint4*)ws)[(size_t)f * 512 + kk * 256 + tid] = fr.u;
    } else {
        float klacc = 0.f;
        _Float16* w0h = (_Float16*)(ws + W0HOFF);
        _Float16* b0h = (_Float16*)(ws + B0HOFF);
        for (int idx = (bx - 128) * 256 + tid; idx < 16448; idx += 2048) {
            const float *mu, *ls, *ew;
            int j, kind; float scale;
            if (idx < 4096)       { j = idx;         mu = wmu0; ls = wls0; ew = ew0; scale = 0.015625f; kind = 0; }
            else if (idx < 8192)  { j = idx - 4096;  mu = bmu0; ls = bls0; ew = eb0; scale = 0.015625f; kind = 1; }
            else if (idx < 12288) { j = idx - 8192;  mu = bmu1; ls = bls1; ew = eb1; scale = 0.015625f; kind = 2; }
            else if (idx < 16384) { j = idx - 12288; mu = wmu2; ls = wls2; ew = ew2; scale = 0.015625f; kind = 3; }
            else                  { j = idx - 16384; mu = bmu2; ls = bls2; ew = eb2; scale = 1.0f;      kind = 4; }
            const float m = mu[j], l = ls[j], e = ew[j];
            const float ex = expf(l);
            const float w  = fmaf(ex, e, m);
            if (kind == 0)      w0h[j] = (_Float16)w;
            else if (kind == 1) b0h[j] = (_Float16)w;
            else if (kind == 2) ws[B1OFF + j] = w;
            else if (kind == 3) ws[W2OFF + j] = w;
            else                ws[B2OFF + j] = w;
            klacc += scale * ((KL_C - l) + 50.f * fmaf(ex, ex, m * m));
        }
        const float bv = bias[0];
        for (int i = (bx - 128) * 256 + tid; i < 16384; i += 2048) out[i] = bv;
        red[tid] = klacc;
        __syncthreads();
        for (int s = 128; s > 0; s >>= 1) {
            if (tid < s) red[tid] += red[tid + s];
            __syncthreads();
        }
        if (tid == 0) ws[KLPOFF + 128 + (bx - 128)] = red[0];
    }
}

// Main: per wave 32 rows x 64 hidden, 4 features per block (16 chunks).
// f16 packed layer-0 (v_pk_fma/v_pk_max), MFMA 16x16x32 f16, fp32 epilogue.
// y partials atomicAdd'ed into d_out (prep initialized it to bias).
__global__ __launch_bounds__(256, 4) void bayesnam_main(const float* __restrict__ fin,
                                                        const float* __restrict__ ws,
                                                        float* __restrict__ out) {
    const int tid = threadIdx.x;
    const int l   = tid & 63;
    const int wid = tid >> 6;
    const int l15 = l & 15;
    const int lg  = l >> 4;
    const int rowbase = blockIdx.x * 128 + wid * 32;
    const int f0 = blockIdx.y * 4;

    // KL finalize (prep partials are ready: same-stream ordering)
    if (blockIdx.x == 0 && blockIdx.y == 0 && tid < 64) {
        float k = 0.f;
        #pragma unroll
        for (int i = 0; i < 3; ++i) {
            const int p = tid + i * 64;
            if (p < 136) k += ws[KLPOFF + p];
        }
        k += __shfl_xor(k, 32, 64); k += __shfl_xor(k, 16, 64); k += __shfl_xor(k, 8, 64);
        k += __shfl_xor(k, 4, 64);  k += __shfl_xor(k, 2, 64);  k += __shfl_xor(k, 1, 64);
        if (tid == 0) out[16384] = k;
    }

    const uint4* __restrict__ w1q = (const uint4*)ws;
    const _Float16* __restrict__ w0h = (const _Float16*)(ws + W0HOFF);
    const _Float16* __restrict__ b0h = (const _Float16*)(ws + B0HOFF);
    const _Float16 negh = (_Float16)0.01f;

    const floatx4 x0v = *(const floatx4*)(fin + (size_t)(rowbase + l15) * 64 + f0);
    const floatx4 x1v = *(const floatx4*)(fin + (size_t)(rowbase + 16 + l15) * 64 + f0);

    float yacc[2][4];
    #pragma unroll
    for (int r = 0; r < 2; ++r)
        #pragma unroll
        for (int q = 0; q < 4; ++q) yacc[r][q] = 0.f;
    float b2sum = 0.f;

    #pragma unroll 1
    for (int fi = 0; fi < 4; ++fi) {
        const int f = f0 + fi;
        const float* b1p = ws + B1OFF + f * 64;
        const float* w2p = ws + W2OFF + f * 64;
        const _Float16 x0h = (_Float16)x0v[fi];
        const _Float16 x1h = (_Float16)x1v[fi];

        floatx4 acc[2][4];
        #pragma unroll
        for (int n = 0; n < 4; ++n) {
            const float bv = b1p[n * 16 + l15];
            acc[0][n] = floatx4{bv, bv, bv, bv};
            acc[1][n] = floatx4{bv, bv, bv, bv};
        }

        #pragma unroll
        for (int kk = 0; kk < 2; ++kk) {
            const int kb = kk * 32 + lg * 8;
            union HU { uint4 u; f16x8 v; };
            HU wu, bu;
            wu.u = *(const uint4*)(w0h + f * 64 + kb);
            bu.u = *(const uint4*)(b0h + f * 64 + kb);

            f16x8 t0 = wu.v * x0h + bu.v;
            f16x8 a0 = __builtin_elementwise_max(t0, t0 * negh);
            f16x8 t1 = wu.v * x1h + bu.v;
            f16x8 a1 = __builtin_elementwise_max(t1, t1 * negh);

            const uint4* bp = w1q + (size_t)(f * 8 + kk * 4) * 64 + l;
            #pragma unroll
            for (int n = 0; n < 4; ++n) {
                HU bf; bf.u = bp[n * 64];
                acc[0][n] = __builtin_amdgcn_mfma_f32_16x16x32_f16(a0, bf.v, acc[0][n], 0, 0, 0);
                acc[1][n] = __builtin_amdgcn_mfma_f32_16x16x32_f16(a1, bf.v, acc[1][n], 0, 0, 0);
            }
        }

        // epilogue: leaky + dot with w2 (fp32)
        #pragma unroll
        for (int n = 0; n < 4; ++n) {
            const float w2v = w2p[n * 16 + l15];
            #pragma unroll
            for (int r = 0; r < 2; ++r)
                #pragma unroll
                for (int q = 0; q < 4; ++q) {
                    float v = acc[r][n][q];
                    v = fmaxf(v, NEG * v);
                    yacc[r][q] = fmaf(v, w2v, yacc[r][q]);
                }
        }
        b2sum += ws[B2OFF + f];
    }

    // reduce over 16 column-lanes (C layout: col = l&15, row = lg*4+q)
    #pragma unroll
    for (int r = 0; r < 2; ++r)
        #pragma unroll
        for (int q = 0; q < 4; ++q) {
            float v = yacc[r][q];
            v += __shfl_xor(v, 1, 64);
            v += __shfl_xor(v, 2, 64);
            v += __shfl_xor(v, 4, 64);
            v += __shfl_xor(v, 8, 64);
            yacc[r][q] = v;
        }
    if (l15 == 0) {
        #pragma unroll
        for (int r = 0; r < 2; ++r)
            #pragma unroll
            for (int q = 0; q < 4; ++q)
                atomicAdd(&out[rowbase + r * 16 + lg * 4 + q], yacc[r][q] + b2sum);
    }
}

extern "C" void kernel_launch(void* const* d_in, const int* in_sizes, int n_in,
                              void* d_out, int out_size, void* d_ws, size_t ws_size,
                              hipStream_t stream) {
    const float* fin  = (const float*)d_in[0];
    const float* wmu0 = (const float*)d_in[1];
    const float* wls0 = (const float*)d_in[2];
    const float* bmu0 = (const float*)d_in[3];
    const float* bls0 = (const float*)d_in[4];
    const float* ew0  = (const float*)d_in[5];
    const float* eb0  = (const float*)d_in[6];
    const float* wmu1 = (const float*)d_in[7];
    const float* wls1 = (const float*)d_in[8];
    const float* bmu1 = (const float*)d_in[9];
    const float* bls1 = (const float*)d_in[10];
    const float* ew1  = (const float*)d_in[11];
    const float* eb1  = (const float*)d_in[12];
    const float* wmu2 = (const float*)d_in[13];
    const float* wls2 = (const float*)d_in[14];
    const float* bmu2 = (const float*)d_in[15];
    const float* bls2 = (const float*)d_in[16];
    const float* ew2  = (const float*)d_in[17];
    const float* eb2  = (const float*)d_in[18];
    const float* bias = (const float*)d_in[19];

    float* ws  = (float*)d_ws;
    float* out = (float*)d_out;

    hipLaunchKernelGGL(bayesnam_prep, dim3(136), dim3(256), 0, stream,
                       wmu0, wls0, bmu0, bls0, ew0, eb0,
                       wmu1, wls1, bmu1, bls1, ew1, eb1,
                       wmu2, wls2, bmu2, bls2, ew2, eb2,
                       bias, ws, out);

    hipLaunchKernelGGL(bayesnam_main, dim3(128, 16), dim3(256), 0, stream,
                       fin, ws, out);
}

// Round 8
// 30.831 us; speedup vs baseline: 3.9163x; 1.0380x over previous
//
#include <hip/hip_runtime.h>
#include <hip/hip_fp16.h>

typedef _Float16 f16x8 __attribute__((ext_vector_type(8)));
typedef float floatx4 __attribute__((ext_vector_type(4)));

#define NEG 0.01f
#define KL_C (-2.8025850929940457f)

// ws layout (float units)
// [0 .. 131071]   W1 f16 MFMA B-fragments: 64 f x 512 uint4 (512 KB)
#define W0HOFF 131072        // 4096 halves
#define B0HOFF 133120        // 4096 halves
#define B1OFF  135168        // 4096 f32
#define W2OFF  139264        // 4096 f32
#define B2OFF  143360        // 64 f32
#define KLPOFF 143424        // 264 f32 partials

// prep grid: blocks 0..255 = (feature f = bx>>2, quarter q = bx&3):
//   16 k-rows of W1 eff (fp32), KL partial, pack f16 fragments.
// blocks 256..263: small tensors (w0,b0,b1,w2,b2) eff + KL, d_out = bias init.
__global__ void bayesnam_prep(const float* __restrict__ wmu0, const float* __restrict__ wls0,
                              const float* __restrict__ bmu0, const float* __restrict__ bls0,
                              const float* __restrict__ ew0,  const float* __restrict__ eb0,
                              const float* __restrict__ wmu1, const float* __restrict__ wls1,
                              const float* __restrict__ bmu1, const float* __restrict__ bls1,
                              const float* __restrict__ ew1,  const float* __restrict__ eb1,
                              const float* __restrict__ wmu2, const float* __restrict__ wls2,
                              const float* __restrict__ bmu2, const float* __restrict__ bls2,
                              const float* __restrict__ ew2,  const float* __restrict__ eb2,
                              const float* __restrict__ bias,
                              float* __restrict__ ws, float* __restrict__ out) {
    const int tid = threadIdx.x;
    const int bx  = blockIdx.x;
    __shared__ float red[256];
    if (bx < 256) {
        const int f = bx >> 2;
        const int q = bx & 3;
        __shared__ float w1s[16 * 65];
        const size_t base = (size_t)f * 4096 + (size_t)q * 1024;
        float klacc = 0.f;
        #pragma unroll
        for (int i = 0; i < 4; ++i) {
            const int idx = i * 256 + tid;           // klocal*64 + col
            const float m = wmu1[base + idx];
            const float l = wls1[base + idx];
            const float e = ew1[base + idx];
            const float ex = expf(l);
            w1s[(idx >> 6) * 65 + (idx & 63)] = fmaf(ex, e, m);
            klacc += (KL_C - l) + 50.f * fmaf(ex, ex, m * m);
        }
        red[tid] = klacc * 0.000244140625f;          // 1/4096 (per-feature mean)
        __syncthreads();
        for (int s = 128; s > 0; s >>= 1) {
            if (tid < s) red[tid] += red[tid + s];
            __syncthreads();
        }
        if (tid == 0) ws[KLPOFF + bx] = red[0];
        // fragment pack: 128 units = n(2b) x lanesub(5b); layout [f][kk][n][lane][8 f16]
        if (tid < 128) {
            const int n   = tid >> 5;
            const int ls  = tid & 31;
            const int s   = ls >> 4;                 // 0..1 (8-row group within quarter)
            const int l15 = ls & 15;
            const int lg  = 2 * (q & 1) + s;
            const int lane = lg * 16 + l15;
            const int kk  = q >> 1;
            const int col = n * 16 + l15;
            union { _Float16 h[8]; uint4 u; } fr;
            #pragma unroll
            for (int j = 0; j < 8; ++j) fr.h[j] = (_Float16)w1s[(8 * s + j) * 65 + col];
            ((uint4*)ws)[(size_t)f * 512 + kk * 256 + n * 64 + lane] = fr.u;
        }
    } else {
        float klacc = 0.f;
        _Float16* w0h = (_Float16*)(ws + W0HOFF);
        _Float16* b0h = (_Float16*)(ws + B0HOFF);
        for (int idx = (bx - 256) * 256 + tid; idx < 16448; idx += 2048) {
            const float *mu, *ls, *ew;
            int j, kind; float scale;
            if (idx < 4096)       { j = idx;         mu = wmu0; ls = wls0; ew = ew0; scale = 0.015625f; kind = 0; }
            else if (idx < 8192)  { j = idx - 4096;  mu = bmu0; ls = bls0; ew = eb0; scale = 0.015625f; kind = 1; }
            else if (idx < 12288) { j = idx - 8192;  mu = bmu1; ls = bls1; ew = eb1; scale = 0.015625f; kind = 2; }
            else if (idx < 16384) { j = idx - 12288; mu = wmu2; ls = wls2; ew = ew2; scale = 0.015625f; kind = 3; }
            else                  { j = idx - 16384; mu = bmu2; ls = bls2; ew = eb2; scale = 1.0f;      kind = 4; }
            const float m = mu[j], l = ls[j], e = ew[j];
            const float ex = expf(l);
            const float w  = fmaf(ex, e, m);
            if (kind == 0)      w0h[j] = (_Float16)w;
            else if (kind == 1) b0h[j] = (_Float16)w;
            else if (kind == 2) ws[B1OFF + j] = w;
            else if (kind == 3) ws[W2OFF + j] = w;
            else                ws[B2OFF + j] = w;
            klacc += scale * ((KL_C - l) + 50.f * fmaf(ex, ex, m * m));
        }
        const float bv = bias[0];
        for (int i = (bx - 256) * 256 + tid; i < 16384; i += 2048) out[i] = bv;
        red[tid] = klacc;
        __syncthreads();
        for (int s = 128; s > 0; s >>= 1) {
            if (tid < s) red[tid] += red[tid + s];
            __syncthreads();
        }
        if (tid == 0) ws[KLPOFF + 256 + (bx - 256)] = red[0];
    }
}

// Main: per wave 32 rows x 64 hidden, 4 features per block (16 chunks).
// W1 fragments staged once per block into LDS (global_load_lds, 32 KB) —
// kills the 256 MB L2 B-fragment re-read that bounded R7.
__global__ __launch_bounds__(256, 4) void bayesnam_main(const float* __restrict__ fin,
                                                        const float* __restrict__ ws,
                                                        float* __restrict__ out) {
    __shared__ uint4 fragLDS[2048];                  // 32 KB: 4 features x 8 KB
    const int tid = threadIdx.x;
    const int l   = tid & 63;
    const int wid = tid >> 6;
    const int l15 = l & 15;
    const int lg  = l >> 4;
    const int rowbase = blockIdx.x * 128 + wid * 32;
    const int f0 = blockIdx.y * 4;

    // stage this chunk's fragments: per-lane global src, wave-uniform LDS dest
    {
        const char* gsrc = (const char*)ws + (size_t)f0 * 8192;
        #pragma unroll
        for (int i = 0; i < 8; ++i) {
            const int chunk = (wid * 8 + i) * 1024;
            __builtin_amdgcn_global_load_lds(
                (const __attribute__((address_space(1))) unsigned int*)(gsrc + chunk + l * 16),
                (__attribute__((address_space(3))) unsigned int*)((char*)fragLDS + chunk),
                16, 0, 0);
        }
    }

    // KL finalize (prep partials ready: same-stream ordering)
    if (blockIdx.x == 0 && blockIdx.y == 0 && tid < 64) {
        float k = 0.f;
        #pragma unroll
        for (int i = 0; i < 5; ++i) {
            const int p = tid + i * 64;
            if (p < 264) k += ws[KLPOFF + p];
        }
        k += __shfl_xor(k, 32, 64); k += __shfl_xor(k, 16, 64); k += __shfl_xor(k, 8, 64);
        k += __shfl_xor(k, 4, 64);  k += __shfl_xor(k, 2, 64);  k += __shfl_xor(k, 1, 64);
        if (tid == 0) out[16384] = k;
    }

    const _Float16* __restrict__ w0h = (const _Float16*)(ws + W0HOFF);
    const _Float16* __restrict__ b0h = (const _Float16*)(ws + B0HOFF);
    const _Float16 negh = (_Float16)0.01f;

    const floatx4 x0v = *(const floatx4*)(fin + (size_t)(rowbase + l15) * 64 + f0);
    const floatx4 x1v = *(const floatx4*)(fin + (size_t)(rowbase + 16 + l15) * 64 + f0);

    __syncthreads();                                 // staging complete

    float yacc[2][4];
    #pragma unroll
    for (int r = 0; r < 2; ++r)
        #pragma unroll
        for (int q = 0; q < 4; ++q) yacc[r][q] = 0.f;
    float b2sum = 0.f;

    #pragma unroll 1
    for (int fi = 0; fi < 4; ++fi) {
        const int f = f0 + fi;
        const float* b1p = ws + B1OFF + f * 64;
        const float* w2p = ws + W2OFF + f * 64;
        const _Float16 x0h = (_Float16)x0v[fi];
        const _Float16 x1h = (_Float16)x1v[fi];

        floatx4 acc[2][4];
        #pragma unroll
        for (int n = 0; n < 4; ++n) {
            const float bv = b1p[n * 16 + l15];
            acc[0][n] = floatx4{bv, bv, bv, bv};
            acc[1][n] = floatx4{bv, bv, bv, bv};
        }

        #pragma unroll
        for (int kk = 0; kk < 2; ++kk) {
            const int kb = kk * 32 + lg * 8;
            union HU { uint4 u; f16x8 v; };
            HU wu, bu;
            wu.u = *(const uint4*)(w0h + f * 64 + kb);
            bu.u = *(const uint4*)(b0h + f * 64 + kb);

            f16x8 t0 = wu.v * x0h + bu.v;
            f16x8 a0 = __builtin_elementwise_max(t0, t0 * negh);
            f16x8 t1 = wu.v * x1h + bu.v;
            f16x8 a1 = __builtin_elementwise_max(t1, t1 * negh);

            const uint4* bp = fragLDS + ((fi * 8 + kk * 4) * 64 + l);
            #pragma unroll
            for (int n = 0; n < 4; ++n) {
                HU bf; bf.u = bp[n * 64];
                acc[0][n] = __builtin_amdgcn_mfma_f32_16x16x32_f16(a0, bf.v, acc[0][n], 0, 0, 0);
                acc[1][n] = __builtin_amdgcn_mfma_f32_16x16x32_f16(a1, bf.v, acc[1][n], 0, 0, 0);
            }
        }

        // epilogue: leaky + dot with w2 (fp32)
        #pragma unroll
        for (int n = 0; n < 4; ++n) {
            const float w2v = w2p[n * 16 + l15];
            #pragma unroll
            for (int r = 0; r < 2; ++r)
                #pragma unroll
                for (int q = 0; q < 4; ++q) {
                    float v = acc[r][n][q];
                    v = fmaxf(v, NEG * v);
                    yacc[r][q] = fmaf(v, w2v, yacc[r][q]);
                }
        }
        b2sum += ws[B2OFF + f];
    }

    // reduce over 16 column-lanes (C layout: col = l&15, row = lg*4+q)
    #pragma unroll
    for (int r = 0; r < 2; ++r)
        #pragma unroll
        for (int q = 0; q < 4; ++q) {
            float v = yacc[r][q];
            v += __shfl_xor(v, 1, 64);
            v += __shfl_xor(v, 2, 64);
            v += __shfl_xor(v, 4, 64);
            v += __shfl_xor(v, 8, 64);
            yacc[r][q] = v;
        }
    if (l15 == 0) {
        #pragma unroll
        for (int r = 0; r < 2; ++r)
            #pragma unroll
            for (int q = 0; q < 4; ++q)
                atomicAdd(&out[rowbase + r * 16 + lg * 4 + q], yacc[r][q] + b2sum);
    }
}

extern "C" void kernel_launch(void* const* d_in, const int* in_sizes, int n_in,
                              void* d_out, int out_size, void* d_ws, size_t ws_size,
                              hipStream_t stream) {
    const float* fin  = (const float*)d_in[0];
    const float* wmu0 = (const float*)d_in[1];
    const float* wls0 = (const float*)d_in[2];
    const float* bmu0 = (const float*)d_in[3];
    const float* bls0 = (const float*)d_in[4];
    const float* ew0  = (const float*)d_in[5];
    const float* eb0  = (const float*)d_in[6];
    const float* wmu1 = (const float*)d_in[7];
    const float* wls1 = (const float*)d_in[8];
    const float* bmu1 = (const float*)d_in[9];
    const float* bls1 = (const float*)d_in[10];
    const float* ew1  = (const float*)d_in[11];
    const float* eb1  = (const float*)d_in[12];
    const float* wmu2 = (const float*)d_in[13];
    const float* wls2 = (const float*)d_in[14];
    const float* bmu2 = (const float*)d_in[15];
    const float* bls2 = (const float*)d_in[16];
    const float* ew2  = (const float*)d_in[17];
    const float* eb2  = (const float*)d_in[18];
    const float* bias = (const float*)d_in[19];

    float* ws  = (float*)d_ws;
    float* out = (float*)d_out;

    hipLaunchKernelGGL(bayesnam_prep, dim3(264), dim3(256), 0, stream,
                       wmu0, wls0, bmu0, bls0, ew0, eb0,
                       wmu1, wls1, bmu1, bls1, ew1, eb1,
                       wmu2, wls2, bmu2, bls2, ew2, eb2,
                       bias, ws, out);

    hipLaunchKernelGGL(bayesnam_main, dim3(128, 16), dim3(256), 0, stream,
                       fin, ws, out);
}